// Round 13
// baseline (454.249 us; speedup 1.0000x reference)
//
#include <hip/hip_runtime.h>
#include <math.h>

// SpectralAttention gfx950 — round 17: flash -> 2 independent blocks/CU.
// R15/R16 post-mortem: two FFT optimizations produced ZERO total change ->
// FFT attribution wrong; stop.  Flash (148us, the largest measured item):
// Mfma 40 + VALU 37, LDS ~50%, no pipe saturated -> ~25% serial-dependency
// stall, unhideable because grid=256 means ONE barrier domain per CU (all 8
// waves stall together at every __syncthreads).  Fix: 256-thread blocks
// (4 waves), t-tile 128 (rg=2 kept), s-step 32, LDS 48KB -> grid 512 = TWO
// independent blocks/CU; co-resident block's waves compute through the other
// block's barrier stalls (verified m114/m97 mechanism; it is why the GEMMs
// at 2 blk/CU work).  Per-wave MFMA/softmax/staging totals unchanged.
// Everything else byte-identical to the passing R16 build (424.8us).
// B=2, T=2048, C=1024, H=16, HD=64.
//
// Packed split format: hi = fp16(v), lo = fp16((v-hi)*2048);
// v = hi + lo/2048 to ~2^-22 rel.  3-term MFMA: D = Ah*Bh + (Ah*Bl + Al*Bh)/2048.
//
// ws layout (floats) with region reuse:
//   [0,  4M)  qT -> qpk -> wopl     [4M, 8M)  kT -> kpk    [8M, 12M) vT -> vpk
//   [12M,16M) w-planes(12MB) -> qipk   [16M,20M) kipk
//   [20M,24M) x-planes(16MB) -> att-planes(16MB)  24M: tables
// total 96 MB + 16 KB

typedef _Float16 half8 __attribute__((ext_vector_type(8)));
typedef _Float16 half4 __attribute__((ext_vector_type(4)));
typedef float f32x4 __attribute__((ext_vector_type(4)));
#define MFMA16 __builtin_amdgcn_mfma_f32_16x16x32_f16

#define GLOAD16(g, l) __builtin_amdgcn_global_load_lds( \
    (const __attribute__((address_space(1))) void*)(g), \
    (__attribute__((address_space(3))) void*)(l), 16, 0, 0)

__device__ inline void split2(float v, _Float16& h, _Float16& l) {
    h = (_Float16)v;
    l = (_Float16)((v - (float)h) * 2048.0f);
}
__device__ inline unsigned pack_split(float v) {
    _Float16 h, l;
    split2(v, h, l);
    union { _Float16 f; unsigned short u; } a, b;
    a.f = h; b.f = l;
    return (unsigned)a.u | ((unsigned)b.u << 16);
}
__device__ inline _Float16 lo16(unsigned u) {
    union { unsigned short s; _Float16 f; } x; x.s = (unsigned short)(u & 0xffffu); return x.f;
}
__device__ inline _Float16 hi16(unsigned u) {
    union { unsigned short s; _Float16 f; } x; x.s = (unsigned short)(u >> 16); return x.f;
}
__device__ inline float2 cmul(float2 a, float2 b) {
    return make_float2(a.x * b.x - a.y * b.y, a.x * b.y + a.y * b.x);
}

// split 8 packed u32 into hi-half8 / lo-half8 via byte-perms, store as 2 b128
__device__ inline void write_split(_Float16* dh, _Float16* dl, uint4 u0, uint4 u1) {
    uint4 lo, hi;
    lo.x = __builtin_amdgcn_perm(u0.y, u0.x, 0x05040100u);
    lo.y = __builtin_amdgcn_perm(u0.w, u0.z, 0x05040100u);
    lo.z = __builtin_amdgcn_perm(u1.y, u1.x, 0x05040100u);
    lo.w = __builtin_amdgcn_perm(u1.w, u1.z, 0x05040100u);
    hi.x = __builtin_amdgcn_perm(u0.y, u0.x, 0x07060302u);
    hi.y = __builtin_amdgcn_perm(u0.w, u0.z, 0x07060302u);
    hi.z = __builtin_amdgcn_perm(u1.y, u1.x, 0x07060302u);
    hi.w = __builtin_amdgcn_perm(u1.w, u1.z, 0x07060302u);
    *(uint4*)dh = lo;
    *(uint4*)dl = hi;
}

// ---------------------------------------------------------------- init tables
__global__ __launch_bounds__(256) void k_init_tables(
    float2* __restrict__ tw, float2* __restrict__ filt,
    const float* __restrict__ fd, const float* __restrict__ alpha,
    const float* __restrict__ fas)
{
    int i = blockIdx.x * 256 + threadIdx.x;
    double aa = (double)alpha[0] + (double)fas[0] * ((double)fd[0] - 1.5);
    if (i < 1024) {
        double ang = -2.0 * 3.14159265358979323846 * (double)i / 2048.0;
        double s, c;
        sincos(ang, &s, &c);
        tw[i] = make_float2((float)c, (float)s);
    }
    if (i < 2048) {
        double fr = (i < 1024) ? (double)i / 2048.0 : ((double)i - 2048.0) / 2048.0;
        double ph = aa * atan(log(fabs(fr) + 1e-10));
        double s, c;
        sincos(ph, &s, &c);
        filt[i] = make_float2((float)c, (float)s);
    }
}

// ---------------------- prep: W^T -> planar hi/lo planes, MFMA-tiled (x3)
// Plane (halves): [c/16][k/32][lane=64][j=8], lane=(c&15)+16*((k>>3)&3), j=k&7.
__global__ __launch_bounds__(256) void k_prep_wpl3(
    const float* __restrict__ wq, const float* __restrict__ wk,
    const float* __restrict__ wv, _Float16* __restrict__ wpl)
{
    __shared__ float tile[64][65];
    const int z = blockIdx.z;
    const float* W = (z == 0) ? wq : (z == 1) ? wk : wv;
    _Float16* Whi = wpl + (size_t)z * 2097152;
    _Float16* Wlo = Whi + 1048576;
    const int kb = blockIdx.x * 64, cb = blockIdx.y * 64;
    const int t = threadIdx.x, r = t >> 4, c4 = (t & 15) * 4;
#pragma unroll
    for (int i = 0; i < 4; ++i) {
        int row = r + 16 * i;
        float4 v = *(const float4*)&W[(size_t)(kb + row) * 1024 + cb + c4];
        tile[row][c4 + 0] = v.x; tile[row][c4 + 1] = v.y;
        tile[row][c4 + 2] = v.z; tile[row][c4 + 3] = v.w;
    }
    __syncthreads();
#pragma unroll
    for (int h = 0; h < 2; ++h) {
        int idx = t + h * 256;
        int lane = idx & 63, kt2 = (idx >> 6) & 1, ct = idx >> 7;
        int cl = ct * 16 + (lane & 15);
        int kl = kt2 * 32 + ((lane >> 4) * 8);
        half8 hv, lv;
#pragma unroll
        for (int j = 0; j < 8; ++j) {
            _Float16 hh, ll;
            split2(tile[kl + j][cl], hh, ll);
            hv[j] = hh; lv[j] = ll;
        }
        size_t u = ((size_t)((cb >> 4) + ct) * 32 + (kb >> 5) + kt2) * 64 + lane;
        *(half8*)&Whi[u * 8] = hv;
        *(half8*)&Wlo[u * 8] = lv;
    }
}

// ---------------------- prep: single W^T -> planar planes (wo)
__global__ __launch_bounds__(256) void k_prep_wpl1(
    const float* __restrict__ W, _Float16* __restrict__ wpl)
{
    __shared__ float tile[64][65];
    _Float16* Whi = wpl;
    _Float16* Wlo = wpl + 1048576;
    const int kb = blockIdx.x * 64, cb = blockIdx.y * 64;
    const int t = threadIdx.x, r = t >> 4, c4 = (t & 15) * 4;
#pragma unroll
    for (int i = 0; i < 4; ++i) {
        int row = r + 16 * i;
        float4 v = *(const float4*)&W[(size_t)(kb + row) * 1024 + cb + c4];
        tile[row][c4 + 0] = v.x; tile[row][c4 + 1] = v.y;
        tile[row][c4 + 2] = v.z; tile[row][c4 + 3] = v.w;
    }
    __syncthreads();
#pragma unroll
    for (int h = 0; h < 2; ++h) {
        int idx = t + h * 256;
        int lane = idx & 63, kt2 = (idx >> 6) & 1, ct = idx >> 7;
        int cl = ct * 16 + (lane & 15);
        int kl = kt2 * 32 + ((lane >> 4) * 8);
        half8 hv, lv;
#pragma unroll
        for (int j = 0; j < 8; ++j) {
            _Float16 hh, ll;
            split2(tile[kl + j][cl], hh, ll);
            hv[j] = hh; lv[j] = ll;
        }
        size_t u = ((size_t)((cb >> 4) + ct) * 32 + (kb >> 5) + kt2) * 64 + lane;
        *(half8*)&Whi[u * 8] = hv;
        *(half8*)&Wlo[u * 8] = lv;
    }
}

// ---------------------- prep: x -> planar hi/lo planes, MFMA-tiled
__global__ __launch_bounds__(256) void k_prep_xpl(
    const float* __restrict__ x, _Float16* __restrict__ xpl)
{
    __shared__ float tile[64][65];
    _Float16* Xhi = xpl;
    _Float16* Xlo = xpl + 4194304;
    const int nb = blockIdx.x * 64, cb = blockIdx.y * 64;
    const int t = threadIdx.x, r = t >> 4, c4 = (t & 15) * 4;
#pragma unroll
    for (int i = 0; i < 4; ++i) {
        int row = r + 16 * i;
        float4 v = *(const float4*)&x[(size_t)(nb + row) * 1024 + cb + c4];
        tile[row][c4 + 0] = v.x; tile[row][c4 + 1] = v.y;
        tile[row][c4 + 2] = v.z; tile[row][c4 + 3] = v.w;
    }
    __syncthreads();
#pragma unroll
    for (int h = 0; h < 2; ++h) {
        int idx = t + h * 256;
        int lane = idx & 63, ct2 = (idx >> 6) & 1, ntl = (idx >> 7) & 3;
        int nl = ntl * 16 + (lane & 15);
        int cl = ct2 * 32 + ((lane >> 4) * 8);
        half8 hv, lv;
#pragma unroll
        for (int j = 0; j < 8; ++j) {
            _Float16 hh, ll;
            split2(tile[nl][cl + j], hh, ll);
            hv[j] = hh; lv[j] = ll;
        }
        size_t u = ((size_t)((nb >> 4) + ntl) * 32 + (cb >> 5) + ct2) * 64 + lane;
        *(half8*)&Xhi[u * 8] = hv;
        *(half8*)&Xlo[u * 8] = lv;
    }
}

// --------------------------------------------------- QKV GEMM (MFMA f16-split)
// R14: double-buffered LDS + early-issue global_load_lds, 1 barrier/iter.
__global__ __launch_bounds__(256) void k_gemm_qkv(
    const _Float16* __restrict__ xpl, const _Float16* __restrict__ wpl,
    const float* __restrict__ bq, const float* __restrict__ bk,
    const float* __restrict__ bv,
    float* __restrict__ qT, float* __restrict__ kT, float* __restrict__ vT)
{
    __shared__ __align__(16) _Float16 Ab[2][8][2][64][8];   // 32 KB
    __shared__ __align__(16) _Float16 Bb[2][8][2][64][8];   // 32 KB
    const int tid = threadIdx.x;
    const int mat = blockIdx.z;
    const _Float16* Ahi = wpl + (size_t)mat * 2097152;
    const _Float16* Alo = Ahi + 1048576;
    const _Float16* Bhi = xpl;
    const _Float16* Blo = xpl + 4194304;
    const float* bias = (mat == 0) ? bq : (mat == 1) ? bk : bv;
    float* outp       = (mat == 0) ? qT : (mat == 1) ? kT : vT;
    const int m0 = blockIdx.x * 128, n0 = blockIdx.y * 128;
    const int w = tid >> 6, lane = tid & 63, quad = lane >> 4, l15 = lane & 15;
    const int wm = (w & 1) * 4, wn = (w >> 1) * 4;

    const int s0 = 2 * w, s1 = 2 * w + 1;
    const size_t aT0 = (size_t)((m0 >> 4) + s0) * 32;
    const size_t aT1 = aT0 + 32;
    const size_t bT0 = (size_t)((n0 >> 4) + s0) * 32;
    const size_t bT1 = bT0 + 32;
    const int ln8 = lane * 8;

    f32x4 acc1[4][4], acc2[4][4];
    const f32x4 z4 = {0.f, 0.f, 0.f, 0.f};
#pragma unroll
    for (int i = 0; i < 4; ++i)
#pragma unroll
        for (int j = 0; j < 4; ++j) { acc1[i][j] = z4; acc2[i][j] = z4; }

    {
        size_t oA0 = aT0 * 512 + ln8;
        size_t oA1 = aT1 * 512 + ln8;
        size_t oB0 = bT0 * 512 + ln8;
        size_t oB1 = bT1 * 512 + ln8;
        GLOAD16(Ahi + oA0, &Ab[0][s0][0][0][0]);
        GLOAD16(Alo + oA0, &Ab[0][s0][1][0][0]);
        GLOAD16(Ahi + oA1, &Ab[0][s1][0][0][0]);
        GLOAD16(Alo + oA1, &Ab[0][s1][1][0][0]);
        GLOAD16(Bhi + oB0, &Bb[0][s0][0][0][0]);
        GLOAD16(Blo + oB0, &Bb[0][s0][1][0][0]);
        GLOAD16(Bhi + oB1, &Bb[0][s1][0][0][0]);
        GLOAD16(Blo + oB1, &Bb[0][s1][1][0][0]);
    }
    __syncthreads();

    for (int kt = 0; kt < 32; ++kt) {
        const int cur = kt & 1, nxt = cur ^ 1;
        if (kt < 31) {
            int kn = kt + 1;
            size_t oA0 = (aT0 + kn) * 512 + ln8;
            size_t oA1 = (aT1 + kn) * 512 + ln8;
            size_t oB0 = (bT0 + kn) * 512 + ln8;
            size_t oB1 = (bT1 + kn) * 512 + ln8;
            GLOAD16(Ahi + oA0, &Ab[nxt][s0][0][0][0]);
            GLOAD16(Alo + oA0, &Ab[nxt][s0][1][0][0]);
            GLOAD16(Ahi + oA1, &Ab[nxt][s1][0][0][0]);
            GLOAD16(Alo + oA1, &Ab[nxt][s1][1][0][0]);
            GLOAD16(Bhi + oB0, &Bb[nxt][s0][0][0][0]);
            GLOAD16(Blo + oB0, &Bb[nxt][s0][1][0][0]);
            GLOAD16(Bhi + oB1, &Bb[nxt][s1][0][0][0]);
            GLOAD16(Blo + oB1, &Bb[nxt][s1][1][0][0]);
        }
        half8 ah[4], al[4];
#pragma unroll
        for (int mt = 0; mt < 4; ++mt) {
            ah[mt] = *(half8*)&Ab[cur][wm + mt][0][lane][0];
            al[mt] = *(half8*)&Ab[cur][wm + mt][1][lane][0];
        }
#pragma unroll
        for (int nt = 0; nt < 4; ++nt) {
            half8 bh = *(half8*)&Bb[cur][wn + nt][0][lane][0];
            half8 bl = *(half8*)&Bb[cur][wn + nt][1][lane][0];
#pragma unroll
            for (int mt = 0; mt < 4; ++mt) {
                acc1[mt][nt] = MFMA16(ah[mt], bh, acc1[mt][nt], 0, 0, 0);
                acc2[mt][nt] = MFMA16(ah[mt], bl, acc2[mt][nt], 0, 0, 0);
                acc2[mt][nt] = MFMA16(al[mt], bh, acc2[mt][nt], 0, 0, 0);
            }
        }
        __syncthreads();
    }
    const int b_ = n0 >> 11, t0 = n0 & 2047;
#pragma unroll
    for (int mt = 0; mt < 4; ++mt) {
#pragma unroll
        for (int r_ = 0; r_ < 4; ++r_) {
            int m = m0 + (wm + mt) * 16 + quad * 4 + r_;
            float bs = bias[m];
            float* orow = &outp[(size_t)(b_ * 1024 + m) * 2048 + t0];
#pragma unroll
            for (int nt = 0; nt < 4; ++nt) {
                float val = acc1[mt][nt][r_] + acc2[mt][nt][r_] * (1.f / 2048.f) + bs;
                orow[(wn + nt) * 16 + l15] = val;
            }
        }
    }
}

// ------------------------------------------------------------- FFT + filter
// Real-FFT pairing + radix-4 butterflies + padded LDS (SFI).
#define SFI(i) ((i) + ((i) >> 4))
__global__ __launch_bounds__(256) void k_fft_filter(
    float* __restrict__ qT, float* __restrict__ kT, float* __restrict__ vT,
    float* __restrict__ qiT, float* __restrict__ kiT,
    const float2* __restrict__ tw, const float2* __restrict__ filt)
{
    __shared__ float2 sf[2176];          // 2048 + 128 pad
    const int bid = blockIdx.x;          // 0..3071
    const int mat = bid >> 10;
    const int pair = bid & 1023;
    const int seq0 = pair * 2, seq1 = seq0 + 1;
    float* base = (mat == 0) ? qT : (mat == 1) ? kT : vT;
    float* src0 = base + (size_t)seq0 * 2048;
    float* src1 = base + (size_t)seq1 * 2048;
    const int tid = threadIdx.x;

    for (int i = tid; i < 2048; i += 256) {
        int j = (int)(__brev((unsigned)i) >> 21);
        sf[SFI(j)] = make_float2(src0[i], src1[i]);
    }
    __syncthreads();
    // radix-4 passes: stages (1,2),(3,4),(5,6),(7,8),(9,10)
#pragma unroll
    for (int st = 1; st <= 9; st += 2) {
        const int h = 1 << (st - 1);
        const int s = 11 - st;
        for (int u = tid; u < 512; u += 256) {
            int m = u & (h - 1);
            int g = u >> (st - 1);
            int bi = g * 4 * h + m;
            float2 a = sf[SFI(bi)], b = sf[SFI(bi + h)];
            float2 c = sf[SFI(bi + 2 * h)], d = sf[SFI(bi + 3 * h)];
            float2 W  = tw[m << s];
            float2 W2 = tw[m << (s - 1)];
            float2 wb = cmul(W, b), wd = cmul(W, d);
            float2 a1 = make_float2(a.x + wb.x, a.y + wb.y);
            float2 b1 = make_float2(a.x - wb.x, a.y - wb.y);
            float2 c1 = make_float2(c.x + wd.x, c.y + wd.y);
            float2 d1 = make_float2(c.x - wd.x, c.y - wd.y);
            float2 w2c = cmul(W2, c1);
            float2 w2d = cmul(W2, d1);
            float2 w3d = make_float2(w2d.y, -w2d.x);   // -i * w2d
            sf[SFI(bi)]         = make_float2(a1.x + w2c.x, a1.y + w2c.y);
            sf[SFI(bi + 2 * h)] = make_float2(a1.x - w2c.x, a1.y - w2c.y);
            sf[SFI(bi + h)]     = make_float2(b1.x + w3d.x, b1.y + w3d.y);
            sf[SFI(bi + 3 * h)] = make_float2(b1.x - w3d.x, b1.y - w3d.y);
        }
        __syncthreads();
    }
    // final radix-2 stage 11: half = 1024
    for (int u = tid; u < 1024; u += 256) {
        float2 w = tw[u];
        float2 a = sf[SFI(u)], b = sf[SFI(u + 1024)];
        float2 wb = cmul(w, b);
        sf[SFI(u)]        = make_float2(a.x + wb.x, a.y + wb.y);
        sf[SFI(u + 1024)] = make_float2(a.x - wb.x, a.y - wb.y);
    }
    __syncthreads();

    unsigned* dr0 = (unsigned*)src0;
    unsigned* dr1 = (unsigned*)src1;
    unsigned* di0 = (mat == 0) ? (unsigned*)(qiT + (size_t)seq0 * 2048)
                               : (unsigned*)(kiT + (size_t)seq0 * 2048);
    unsigned* di1 = (mat == 0) ? (unsigned*)(qiT + (size_t)seq1 * 2048)
                               : (unsigned*)(kiT + (size_t)seq1 * 2048);
    for (int i = tid; i < 2048; i += 256) {
        float2 z  = sf[SFI(i)];
        float2 zm = sf[SFI((2048 - i) & 2047)];
        float Are = 0.5f * (z.x + zm.x), Aim = 0.5f * (z.y - zm.y);
        float Bre = 0.5f * (z.y + zm.y), Bim = 0.5f * (zm.x - z.x);
        float2 f = filt[i];
        float re0 = Are * f.x - Aim * f.y, im0 = Are * f.y + Aim * f.x;
        float re1 = Bre * f.x - Bim * f.y, im1 = Bre * f.y + Bim * f.x;
        if (mat == 0) {
            dr0[i] = pack_split(0.125f * re0); di0[i] = pack_split(0.125f * im0);
            dr1[i] = pack_split(0.125f * re1); di1[i] = pack_split(0.125f * im1);
        } else if (mat == 1) {
            dr0[i] = pack_split(re0); di0[i] = pack_split(-im0);
            dr1[i] = pack_split(re1); di1[i] = pack_split(-im1);
        } else {
            dr0[i] = pack_split(re0);
            dr1[i] = pack_split(re1);
        }
    }
}

// ------------------------------------------------------------- flash (MFMA f16)
// R17: 512 blocks x 256 thr (4 waves) = 2 independent blocks/CU; t-tile 128
// (wave owns 32 rows = 2 rg); s-step 32; dbuf K/V (48KB), ONE barrier/iter,
// 64 iters.  S^T=MFMA(K,Q); per-lane softmax + defer-max(THR=8);
// O^T=MFMA(V,P-reg) under 32-wide sigma(q,j)=16(j>>2)+4q+(j&3).
__global__ __launch_bounds__(256, 2) void k_flash(
    const unsigned* __restrict__ qpk, const unsigned* __restrict__ qipk,
    const unsigned* __restrict__ kpk, const unsigned* __restrict__ kipk,
    const unsigned* __restrict__ vpk, _Float16* __restrict__ attpl)
{
    __shared__ __align__(16) _Float16 Kbuf[2][2][4][2][64][8];  // 32KB [db][st][kc][hl][lane][j]
    __shared__ __align__(16) _Float16 Vbuf[2][4][2][64][8];     // 16KB [db][nt][hl][lane][j]

    const int tid = threadIdx.x;
    const int w = tid >> 6, lane = tid & 63;
    const int quad = lane >> 4, l15 = lane & 15;
    // XCD swizzle over 512 blocks: p = c + 8*tb + 128*u -> bh = c*4+u, tb 0..15.
    const int p = blockIdx.x;
    const int bh = (p & 7) * 4 + (p >> 7);
    const int tb = (p >> 3) & 15;
    const size_t bc = (size_t)bh * 64;
    const int tw0 = tb * 128 + w * 16;   // rg adds +64

    // Q frags (B-operand for S^T)
    half8 aqh[2][4], aql[2][4];
#pragma unroll
    for (int rg = 0; rg < 2; ++rg) {
#pragma unroll
        for (int kc = 0; kc < 4; ++kc) {
#pragma unroll
            for (int j = 0; j < 8; ++j) {
                int d = kc * 32 + quad * 8 + j;
                int t = tw0 + rg * 64 + l15;
                unsigned u = (d < 64) ? qpk[(bc + d) * 2048 + t]
                                      : qipk[(bc + d - 64) * 2048 + t];
                aqh[rg][kc][j] = lo16(u);
                aql[rg][kc][j] = hi16(u);
            }
        }
    }

    f32x4 O1[2][4], O2[2][4];
    const f32x4 zero4 = {0.f, 0.f, 0.f, 0.f};
#pragma unroll
    for (int rg = 0; rg < 2; ++rg)
#pragma unroll
        for (int nt = 0; nt < 4; ++nt) { O1[rg][nt] = zero4; O2[rg][nt] = zero4; }
    float m_[2] = {-3e38f, -3e38f};
    float l_[2] = {0.f, 0.f};

    // K staging: 32 s x 128 d (re 0..63, im 64..127); 256 thr x (8 re + 8 im)
    const int sK = tid & 31;           // s within tile
    const int dgK = tid >> 5;          // 0..7: d chunk dgK (re), dgK (im)
    const int stK = sK >> 4;           // 0..1
    const int kcK0 = dgK >> 2;         // 0..1; im kc = kcK0+2
    const int laneK = (sK & 15) + ((dgK & 3) << 4);
    const unsigned* kre = &kpk[(bc + dgK * 8) * 2048 + sK];
    const unsigned* kim = &kipk[(bc + dgK * 8) * 2048 + sK];
    // V staging: 64 d x 32 s; 256 thr x 8 u32 (two uint4 at s=4q and s=16+4q)
    const int ntV = tid >> 6, laneV = tid & 63;
    const int dV = ntV * 16 + (laneV & 15);
    const int qV4 = (laneV >> 4) * 4;
    const unsigned* vbase = &vpk[(bc + dV) * 2048 + qV4];

    // ---- prologue: tile 0 -> buf0; prefetch tile 1 into named scalars
    unsigned ka0, ka1, ka2, ka3, ka4, ka5, ka6, ka7;
    unsigned kb0, kb1, kb2, kb3, kb4, kb5, kb6, kb7;
    uint4 va0, va1;
    ka0 = kre[0 * 2048]; ka1 = kre[1 * 2048];
    ka2 = kre[2 * 2048]; ka3 = kre[3 * 2048];
    ka4 = kre[4 * 2048]; ka5 = kre[5 * 2048];
    ka6 = kre[6 * 2048]; ka7 = kre[7 * 2048];
    kb0 = kim[0 * 2048]; kb1 = kim[1 * 2048];
    kb2 = kim[2 * 2048]; kb3 = kim[3 * 2048];
    kb4 = kim[4 * 2048]; kb5 = kim[5 * 2048];
    kb6 = kim[6 * 2048]; kb7 = kim[7 * 2048];
    va0 = *(const uint4*)vbase;
    va1 = *(const uint4*)(vbase + 16);
    write_split(&Kbuf[0][stK][kcK0][0][laneK][0], &Kbuf[0][stK][kcK0][1][laneK][0],
                make_uint4(ka0, ka1, ka2, ka3), make_uint4(ka4, ka5, ka6, ka7));
    write_split(&Kbuf[0][stK][kcK0 + 2][0][laneK][0], &Kbuf[0][stK][kcK0 + 2][1][laneK][0],
                make_uint4(kb0, kb1, kb2, kb3), make_uint4(kb4, kb5, kb6, kb7));
    write_split(&Vbuf[0][ntV][0][laneV][0], &Vbuf[0][ntV][1][laneV][0], va0, va1);
    kre += 32; kim += 32; vbase += 32;
    ka0 = kre[0 * 2048]; ka1 = kre[1 * 2048];
    ka2 = kre[2 * 2048]; ka3 = kre[3 * 2048];
    ka4 = kre[4 * 2048]; ka5 = kre[5 * 2048];
    ka6 = kre[6 * 2048]; ka7 = kre[7 * 2048];
    kb0 = kim[0 * 2048]; kb1 = kim[1 * 2048];
    kb2 = kim[2 * 2048]; kb3 = kim[3 * 2048];
    kb4 = kim[4 * 2048]; kb5 = kim[5 * 2048];
    kb6 = kim[6 * 2048]; kb7 = kim[7 * 2048];
    va0 = *(const uint4*)vbase;
    va1 = *(const uint4*)(vbase + 16);
    __syncthreads();

    for (int it = 0; it < 64; ++it) {
        const int cur = it & 1, nxt = cur ^ 1;
        // ---- stage tile it+1 into buf[nxt]
        if (it < 63) {
            write_split(&Kbuf[nxt][stK][kcK0][0][laneK][0],
                        &Kbuf[nxt][stK][kcK0][1][laneK][0],
                        make_uint4(ka0, ka1, ka2, ka3), make_uint4(ka4, ka5, ka6, ka7));
            write_split(&Kbuf[nxt][stK][kcK0 + 2][0][laneK][0],
                        &Kbuf[nxt][stK][kcK0 + 2][1][laneK][0],
                        make_uint4(kb0, kb1, kb2, kb3), make_uint4(kb4, kb5, kb6, kb7));
            write_split(&Vbuf[nxt][ntV][0][laneV][0],
                        &Vbuf[nxt][ntV][1][laneV][0], va0, va1);
        }
        // ---- issue loads for tile it+2
        if (it < 62) {
            kre += 32; kim += 32; vbase += 32;
            ka0 = kre[0 * 2048]; ka1 = kre[1 * 2048];
            ka2 = kre[2 * 2048]; ka3 = kre[3 * 2048];
            ka4 = kre[4 * 2048]; ka5 = kre[5 * 2048];
            ka6 = kre[6 * 2048]; ka7 = kre[7 * 2048];
            kb0 = kim[0 * 2048]; kb1 = kim[1 * 2048];
            kb2 = kim[2 * 2048]; kb3 = kim[3 * 2048];
            kb4 = kim[4 * 2048]; kb5 = kim[5 * 2048];
            kb6 = kim[6 * 2048]; kb7 = kim[7 * 2048];
            va0 = *(const uint4*)vbase;
            va1 = *(const uint4*)(vbase + 16);
        }

        // --- S^T = K.Q^T: 48 MFMA, K read once for both rg
        f32x4 S1[2][2], S2[2][2];
#pragma unroll
        for (int rg = 0; rg < 2; ++rg)
#pragma unroll
            for (int st = 0; st < 2; ++st) { S1[rg][st] = zero4; S2[rg][st] = zero4; }
        __builtin_amdgcn_s_setprio(1);
#pragma unroll
        for (int st = 0; st < 2; ++st) {
#pragma unroll
            for (int kc = 0; kc < 4; ++kc) {
                half8 khf = *(half8*)&Kbuf[cur][st][kc][0][lane][0];
                half8 klf = *(half8*)&Kbuf[cur][st][kc][1][lane][0];
#pragma unroll
                for (int rg = 0; rg < 2; ++rg) {
                    S1[rg][st] = MFMA16(khf, aqh[rg][kc], S1[rg][st], 0, 0, 0);
                    S2[rg][st] = MFMA16(klf, aqh[rg][kc], S2[rg][st], 0, 0, 0);
                    S2[rg][st] = MFMA16(khf, aql[rg][kc], S2[rg][st], 0, 0, 0);
                }
            }
        }
        __builtin_amdgcn_s_setprio(0);

        // --- per-lane online softmax with defer-max (THR=8)
        half8 pb[2];
#pragma unroll
        for (int rg = 0; rg < 2; ++rg) {
#pragma unroll
            for (int st = 0; st < 2; ++st)
                S1[rg][st] = S1[rg][st] + S2[rg][st] * (1.f / 2048.f);
            float mt = -3e38f;
#pragma unroll
            for (int st = 0; st < 2; ++st)
#pragma unroll
                for (int r = 0; r < 4; ++r)
                    mt = fmaxf(mt, S1[rg][st][r]);
            mt = fmaxf(mt, __shfl_xor(mt, 16));
            mt = fmaxf(mt, __shfl_xor(mt, 32));
            if (!__all(mt <= m_[rg] + 8.f)) {
                float mn2 = fmaxf(m_[rg], mt);
                float al = __expf(m_[rg] - mn2);
                m_[rg] = mn2;
                l_[rg] *= al;
#pragma unroll
                for (int nt = 0; nt < 4; ++nt) { O1[rg][nt] *= al; O2[rg][nt] *= al; }
            }
            float mn = m_[rg];
            float rs = 0.f;
            _Float16 ph[2][4];
#pragma unroll
            for (int st = 0; st < 2; ++st)
#pragma unroll
                for (int r = 0; r < 4; ++r) {
                    float pe = __expf(S1[rg][st][r] - mn);
                    rs += pe;
                    ph[st][r] = (_Float16)pe;
                }
            rs += __shfl_xor(rs, 16);
            rs += __shfl_xor(rs, 32);
            l_[rg] += rs;
            half8 t8;
            t8[0] = ph[0][0]; t8[1] = ph[0][1];
            t8[2] = ph[0][2]; t8[3] = ph[0][3];
            t8[4] = ph[1][0]; t8[5] = ph[1][1];
            t8[6] = ph[1][2]; t8[7] = ph[1][3];
            pb[rg] = t8;
        }

        // --- PV as O^T = MFMA(Vfrag, P): 16 MFMA, V read once for both rg
        __builtin_amdgcn_s_setprio(1);
#pragma unroll
        for (int nt = 0; nt < 4; ++nt) {
            half8 vh = *(half8*)&Vbuf[cur][nt][0][lane][0];
            half8 vl = *(half8*)&Vbuf[cur][nt][1][lane][0];
            O1[0][nt] = MFMA16(vh, pb[0], O1[0][nt], 0, 0, 0);
            O2[0][nt] = MFMA16(vl, pb[0], O2[0][nt], 0, 0, 0);
            O1[1][nt] = MFMA16(vh, pb[1], O1[1][nt], 0, 0, 0);
            O2[1][nt] = MFMA16(vl, pb[1], O2[1][nt], 0, 0, 0);
        }
        __builtin_amdgcn_s_setprio(0);

        __syncthreads();   // single barrier per iter (double-buffered)
    }

    // epilogue: write planar planes.  lane holds m = b*2048 + t (t col l15),
    // k = h*64 + nt*16 + quad*4 + r.
    const int b = bh >> 4, h = bh & 15;
#pragma unroll
    for (int rg = 0; rg < 2; ++rg) {
        float inv = 1.0f / l_[rg];
        int mrow = b * 2048 + tw0 + rg * 64 + l15;
        size_t mt32 = (size_t)(mrow >> 4) * 32;
#pragma unroll
        for (int nt = 0; nt < 4; ++nt) {
            size_t u = (mt32 + h * 2 + (nt >> 1)) * 512
                     + (size_t)(l15 + 16 * ((nt * 2 + (quad >> 1)) & 3)) * 8
                     + (quad & 1) * 4;
            half4 hv, lv;
#pragma unroll
            for (int r = 0; r < 4; ++r) {
                float val = (O1[rg][nt][r] + O2[rg][nt][r] * (1.f / 2048.f)) * inv;
                _Float16 hh, ll;
                split2(val, hh, ll);
                hv[r] = hh; lv[r] = ll;
            }
            *(half4*)&attpl[u] = hv;
            *(half4*)&attpl[4194304 + u] = lv;
        }
    }
}

// --------------------------------------------------- out GEMM (MFMA f16-split)
__global__ __launch_bounds__(256) void k_gemm_out(
    const _Float16* __restrict__ attpl, const _Float16* __restrict__ wopl,
    const float* __restrict__ bo, float* __restrict__ out)
{
    __shared__ __align__(16) _Float16 Ab[2][8][2][64][8];   // 32 KB
    __shared__ __align__(16) _Float16 Bb[2][8][2][64][8];   // 32 KB
    const int tid = threadIdx.x;
    const _Float16* Ahi = attpl;
    const _Float16* Alo = attpl + 4194304;
    const _Float16* Bhi = wopl;
    const _Float16* Blo = wopl + 1048576;
    const int m0 = blockIdx.x * 128, n0 = blockIdx.y * 128;
    const int w = tid >> 6, lane = tid & 63, quad = lane >> 4, l15 = lane & 15;
    const int wm = (w & 1) * 4, wn = (w >> 1) * 4;

    const int s0 = 2 * w, s1 = 2 * w + 1;
    const size_t aT0 = (size_t)((m0 >> 4) + s0) * 32;
    const size_t aT1 = aT0 + 32;
    const size_t bT0 = (size_t)((n0 >> 4) + s0) * 32;
    const size_t bT1 = bT0 + 32;
    const int ln8 = lane * 8;

    f32x4 acc1[4][4], acc2[4][4];
    const f32x4 z4 = {0.f, 0.f, 0.f, 0.f};
#pragma unroll
    for (int i = 0; i < 4; ++i)
#pragma unroll
        for (int j = 0; j < 4; ++j) { acc1[i][j] = z4; acc2[i][j] = z4; }

    {
        size_t oA0 = aT0 * 512 + ln8;
        size_t oA1 = aT1 * 512 + ln8;
        size_t oB0 = bT0 * 512 + ln8;
        size_t oB1 = bT1 * 512 + ln8;
        GLOAD16(Ahi + oA0, &Ab[0][s0][0][0][0]);
        GLOAD16(Alo + oA0, &Ab[0][s0][1][0][0]);
        GLOAD16(Ahi + oA1, &Ab[0][s1][0][0][0]);
        GLOAD16(Alo + oA1, &Ab[0][s1][1][0][0]);
        GLOAD16(Bhi + oB0, &Bb[0][s0][0][0][0]);
        GLOAD16(Blo + oB0, &Bb[0][s0][1][0][0]);
        GLOAD16(Bhi + oB1, &Bb[0][s1][0][0][0]);
        GLOAD16(Blo + oB1, &Bb[0][s1][1][0][0]);
    }
    __syncthreads();

    for (int kt = 0; kt < 32; ++kt) {
        const int cur = kt & 1, nxt = cur ^ 1;
        if (kt < 31) {
            int kn = kt + 1;
            size_t oA0 = (aT0 + kn) * 512 + ln8;
            size_t oA1 = (aT1 + kn) * 512 + ln8;
            size_t oB0 = (bT0 + kn) * 512 + ln8;
            size_t oB1 = (bT1 + kn) * 512 + ln8;
            GLOAD16(Ahi + oA0, &Ab[nxt][s0][0][0][0]);
            GLOAD16(Alo + oA0, &Ab[nxt][s0][1][0][0]);
            GLOAD16(Ahi + oA1, &Ab[nxt][s1][0][0][0]);
            GLOAD16(Alo + oA1, &Ab[nxt][s1][1][0][0]);
            GLOAD16(Bhi + oB0, &Bb[nxt][s0][0][0][0]);
            GLOAD16(Blo + oB0, &Bb[nxt][s0][1][0][0]);
            GLOAD16(Bhi + oB1, &Bb[nxt][s1][0][0][0]);
            GLOAD16(Blo + oB1, &Bb[nxt][s1][1][0][0]);
        }
        half8 ah[4], al[4];
#pragma unroll
        for (int mt = 0; mt < 4; ++mt) {
            ah[mt] = *(half8*)&Ab[cur][wm + mt][0][lane][0];
            al[mt] = *(half8*)&Ab[cur][wm + mt][1][lane][0];
        }
#pragma unroll
        for (int nt = 0; nt < 4; ++nt) {
            half8 bh = *(half8*)&Bb[cur][wn + nt][0][lane][0];
            half8 bl = *(half8*)&Bb[cur][wn + nt][1][lane][0];
#pragma unroll
            for (int mt = 0; mt < 4; ++mt) {
                acc1[mt][nt] = MFMA16(ah[mt], bh, acc1[mt][nt], 0, 0, 0);
                acc2[mt][nt] = MFMA16(ah[mt], bl, acc2[mt][nt], 0, 0, 0);
                acc2[mt][nt] = MFMA16(al[mt], bh, acc2[mt][nt], 0, 0, 0);
            }
        }
        __syncthreads();
    }
#pragma unroll
    for (int mt = 0; mt < 4; ++mt) {
#pragma unroll
        for (int r_ = 0; r_ < 4; ++r_) {
            int m = m0 + (wm + mt) * 16 + quad * 4 + r_;
            float* orow = &out[(size_t)m * 1024 + n0];
#pragma unroll
            for (int nt = 0; nt < 4; ++nt) {
                int n = (wn + nt) * 16 + l15;
                float val = acc1[mt][nt][r_] + acc2[mt][nt][r_] * (1.f / 2048.f)
                          + bo[n0 + n];
                orow[n] = val;
            }
        }
    }
}

// ------------------------------------------------------------- energy renorm
__global__ __launch_bounds__(256) void k_norm(
    const float* __restrict__ x, float* __restrict__ out,
    const float* __restrict__ en)
{
    const int row = blockIdx.x;
    const int tid = threadIdx.x;
    const float* xr = x + (size_t)row * 1024;
    float* orow = out + (size_t)row * 1024;
    float4 xv = *(const float4*)&xr[tid * 4];
    float4 ov = *(const float4*)&orow[tid * 4];
    float ssx = xv.x * xv.x + xv.y * xv.y + xv.z * xv.z + xv.w * xv.w;
    float sso = ov.x * ov.x + ov.y * ov.y + ov.z * ov.z + ov.w * ov.w;
#pragma unroll
    for (int m = 1; m <= 32; m <<= 1) {
        ssx += __shfl_xor(ssx, m, 64);
        sso += __shfl_xor(sso, m, 64);
    }
    __shared__ float rx[4], ro[4];
    const int wid = tid >> 6;
    if ((tid & 63) == 0) { rx[wid] = ssx; ro[wid] = sso; }
    __syncthreads();
    float tsx = rx[0] + rx[1] + rx[2] + rx[3];
    float tso = ro[0] + ro[1] + ro[2] + ro[3];
    float scale = sqrtf(tsx) / (sqrtf(tso) + 1e-8f) * en[0];
    ov.x *= scale; ov.y *= scale; ov.z *= scale; ov.w *= scale;
    *(float4*)&orow[tid * 4] = ov;
}

// ------------------------------------------------------------- launch
extern "C" void kernel_launch(void* const* d_in, const int* in_sizes, int n_in,
                              void* d_out, int out_size, void* d_ws, size_t ws_size,
                              hipStream_t stream)
{
    const float* x     = (const float*)d_in[0];
    const float* fd    = (const float*)d_in[1];
    const float* wq    = (const float*)d_in[2];
    const float* bq    = (const float*)d_in[3];
    const float* wk    = (const float*)d_in[4];
    const float* bk    = (const float*)d_in[5];
    const float* wv    = (const float*)d_in[6];
    const float* bv    = (const float*)d_in[7];
    const float* wo    = (const float*)d_in[8];
    const float* bo    = (const float*)d_in[9];
    const float* alpha = (const float*)d_in[10];
    const float* fas   = (const float*)d_in[11];
    const float* en    = (const float*)d_in[12];
    float* out = (float*)d_out;
    float* ws  = (float*)d_ws;

    float* qT  = ws;                               // -> qpk -> wopl
    float* kT  = ws + (size_t)1 * 4194304;         // -> kpk
    float* vT  = ws + (size_t)2 * 4194304;         // -> vpk
    float* qiT = ws + (size_t)3 * 4194304;         // w-planes -> qipk
    float* kiT = ws + (size_t)4 * 4194304;         // -> kipk
    float* att = ws + (size_t)5 * 4194304;         // x-planes -> att-planes
    float2* tw   = (float2*)(ws + (size_t)6 * 4194304);
    float2* filt = (float2*)(ws + (size_t)6 * 4194304 + 2048);

    _Float16* wpl   = (_Float16*)qiT;    // 3 x (2MB hi + 2MB lo) = 12MB
    _Float16* xpl   = (_Float16*)att;    // 8MB hi + 8MB lo = 16MB
    _Float16* attpl = (_Float16*)att;    // 8MB hi + 8MB lo (after xpl dead)
    _Float16* wopl  = (_Float16*)qT;     // 2MB hi + 2MB lo (after flash)

    k_init_tables<<<8, 256, 0, stream>>>(tw, filt, fd, alpha, fas);
    k_prep_wpl3<<<dim3(16, 16, 3), 256, 0, stream>>>(wq, wk, wv, wpl);
    k_prep_xpl<<<dim3(64, 16), 256, 0, stream>>>(x, xpl);
    k_gemm_qkv<<<dim3(8, 32, 3), 256, 0, stream>>>(xpl, wpl, bq, bk, bv,
                                                   qT, kT, vT);
    k_fft_filter<<<3072, 256, 0, stream>>>(qT, kT, vT, qiT, kiT, tw, filt);
    k_flash<<<512, 256, 0, stream>>>((const unsigned*)qT, (const unsigned*)qiT,
                                     (const unsigned*)kT, (const unsigned*)kiT,
                                     (const unsigned*)vT, attpl);
    k_prep_wpl1<<<dim3(16, 16), 256, 0, stream>>>(wo, wopl);
    k_gemm_out<<<dim3(32, 8), 256, 0, stream>>>(attpl, wopl, bo, out);
    k_norm<<<4096, 256, 0, stream>>>(x, out, en);
}

// Round 14
// 418.485 us; speedup vs baseline: 1.0855x; 1.0855x over previous
//
#include <hip/hip_runtime.h>
#include <math.h>

// SpectralAttention gfx950 — round 18: revert flash (R17's 4-wave split
// regressed 147->169us: doubled iter count doubled per-iter fixed costs) and
// attack launch overhead: the non-flash 276us exceeds compute models by
// ~130us ~= 9 serial launches x ~15us.  Fuse the three INDEPENDENT front
// kernels (init_tables 8 blk, prep_wpl3 768 blk, prep_xpl 1024 blk) into one
// 1800-block kernel (branch on blockIdx range; disjoint outputs) -> 7
// launches, preps co-scheduled.  prep_wpl1 stays (output aliases qT, live
// until flash).  Flash/gemms/FFT byte-identical to R16 (423.4us verified).
// B=2, T=2048, C=1024, H=16, HD=64.
//
// Packed split format: hi = fp16(v), lo = fp16((v-hi)*2048);
// v = hi + lo/2048 to ~2^-22 rel.  3-term MFMA: D = Ah*Bh + (Ah*Bl + Al*Bh)/2048.
//
// ws layout (floats) with region reuse:
//   [0,  4M)  qT -> qpk -> wopl     [4M, 8M)  kT -> kpk    [8M, 12M) vT -> vpk
//   [12M,16M) w-planes(12MB) -> qipk   [16M,20M) kipk
//   [20M,24M) x-planes(16MB) -> att-planes(16MB)  24M: tables
// total 96 MB + 16 KB

typedef _Float16 half8 __attribute__((ext_vector_type(8)));
typedef _Float16 half4 __attribute__((ext_vector_type(4)));
typedef float f32x4 __attribute__((ext_vector_type(4)));
#define MFMA16 __builtin_amdgcn_mfma_f32_16x16x32_f16

#define GLOAD16(g, l) __builtin_amdgcn_global_load_lds( \
    (const __attribute__((address_space(1))) void*)(g), \
    (__attribute__((address_space(3))) void*)(l), 16, 0, 0)

__device__ inline void split2(float v, _Float16& h, _Float16& l) {
    h = (_Float16)v;
    l = (_Float16)((v - (float)h) * 2048.0f);
}
__device__ inline unsigned pack_split(float v) {
    _Float16 h, l;
    split2(v, h, l);
    union { _Float16 f; unsigned short u; } a, b;
    a.f = h; b.f = l;
    return (unsigned)a.u | ((unsigned)b.u << 16);
}
__device__ inline _Float16 lo16(unsigned u) {
    union { unsigned short s; _Float16 f; } x; x.s = (unsigned short)(u & 0xffffu); return x.f;
}
__device__ inline _Float16 hi16(unsigned u) {
    union { unsigned short s; _Float16 f; } x; x.s = (unsigned short)(u >> 16); return x.f;
}
__device__ inline float2 cmul(float2 a, float2 b) {
    return make_float2(a.x * b.x - a.y * b.y, a.x * b.y + a.y * b.x);
}

// split 8 packed u32 into hi-half8 / lo-half8 via byte-perms, store as 2 b128
__device__ inline void write_split(_Float16* dh, _Float16* dl, uint4 u0, uint4 u1) {
    uint4 lo, hi;
    lo.x = __builtin_amdgcn_perm(u0.y, u0.x, 0x05040100u);
    lo.y = __builtin_amdgcn_perm(u0.w, u0.z, 0x05040100u);
    lo.z = __builtin_amdgcn_perm(u1.y, u1.x, 0x05040100u);
    lo.w = __builtin_amdgcn_perm(u1.w, u1.z, 0x05040100u);
    hi.x = __builtin_amdgcn_perm(u0.y, u0.x, 0x07060302u);
    hi.y = __builtin_amdgcn_perm(u0.w, u0.z, 0x07060302u);
    hi.z = __builtin_amdgcn_perm(u1.y, u1.x, 0x07060302u);
    hi.w = __builtin_amdgcn_perm(u1.w, u1.z, 0x07060302u);
    *(uint4*)dh = lo;
    *(uint4*)dl = hi;
}

// ------------------------------------------- fused front: tables + W/x preps
// blocks [0,8): twiddle/filter tables; [8,776): wq/wk/wv -> planar planes;
// [776,1800): x -> planar planes.  All independent, disjoint outputs.
__global__ __launch_bounds__(256) void k_prep_front(
    float2* __restrict__ tw, float2* __restrict__ filt,
    const float* __restrict__ fd, const float* __restrict__ alpha,
    const float* __restrict__ fas,
    const float* __restrict__ wq, const float* __restrict__ wk,
    const float* __restrict__ wv, _Float16* __restrict__ wpl,
    const float* __restrict__ x, _Float16* __restrict__ xpl)
{
    __shared__ float tile[64][65];
    const int bid = blockIdx.x;
    const int t = threadIdx.x;

    if (bid < 8) {
        int i = bid * 256 + t;
        double aa = (double)alpha[0] + (double)fas[0] * ((double)fd[0] - 1.5);
        if (i < 1024) {
            double ang = -2.0 * 3.14159265358979323846 * (double)i / 2048.0;
            double s, c;
            sincos(ang, &s, &c);
            tw[i] = make_float2((float)c, (float)s);
        }
        if (i < 2048) {
            double fr = (i < 1024) ? (double)i / 2048.0 : ((double)i - 2048.0) / 2048.0;
            double ph = aa * atan(log(fabs(fr) + 1e-10));
            double s, c;
            sincos(ph, &s, &c);
            filt[i] = make_float2((float)c, (float)s);
        }
        return;
    }

    if (bid < 776) {
        // W prep: tb in [0,768): z = tb>>8; rem = tb&255: kb=(rem&15)*64, cb=(rem>>4)*64
        const int tb = bid - 8;
        const int z = tb >> 8, rem = tb & 255;
        const float* W = (z == 0) ? wq : (z == 1) ? wk : wv;
        _Float16* Whi = wpl + (size_t)z * 2097152;
        _Float16* Wlo = Whi + 1048576;
        const int kb = (rem & 15) * 64, cb = (rem >> 4) * 64;
        const int r = t >> 4, c4 = (t & 15) * 4;
#pragma unroll
        for (int i = 0; i < 4; ++i) {
            int row = r + 16 * i;
            float4 v = *(const float4*)&W[(size_t)(kb + row) * 1024 + cb + c4];
            tile[row][c4 + 0] = v.x; tile[row][c4 + 1] = v.y;
            tile[row][c4 + 2] = v.z; tile[row][c4 + 3] = v.w;
        }
        __syncthreads();
#pragma unroll
        for (int h = 0; h < 2; ++h) {
            int idx = t + h * 256;
            int lane = idx & 63, kt2 = (idx >> 6) & 1, ct = idx >> 7;
            int cl = ct * 16 + (lane & 15);
            int kl = kt2 * 32 + ((lane >> 4) * 8);
            half8 hv, lv;
#pragma unroll
            for (int j = 0; j < 8; ++j) {
                _Float16 hh, ll;
                split2(tile[kl + j][cl], hh, ll);
                hv[j] = hh; lv[j] = ll;
            }
            size_t u = ((size_t)((cb >> 4) + ct) * 32 + (kb >> 5) + kt2) * 64 + lane;
            *(half8*)&Whi[u * 8] = hv;
            *(half8*)&Wlo[u * 8] = lv;
        }
        return;
    }

    // x prep: tb in [0,1024): nb=(tb&63)*64, cb=(tb>>6)*64
    {
        const int tb = bid - 776;
        _Float16* Xhi = xpl;
        _Float16* Xlo = xpl + 4194304;
        const int nb = (tb & 63) * 64, cb = (tb >> 6) * 64;
        const int r = t >> 4, c4 = (t & 15) * 4;
#pragma unroll
        for (int i = 0; i < 4; ++i) {
            int row = r + 16 * i;
            float4 v = *(const float4*)&x[(size_t)(nb + row) * 1024 + cb + c4];
            tile[row][c4 + 0] = v.x; tile[row][c4 + 1] = v.y;
            tile[row][c4 + 2] = v.z; tile[row][c4 + 3] = v.w;
        }
        __syncthreads();
#pragma unroll
        for (int h = 0; h < 2; ++h) {
            int idx = t + h * 256;
            int lane = idx & 63, ct2 = (idx >> 6) & 1, ntl = (idx >> 7) & 3;
            int nl = ntl * 16 + (lane & 15);
            int cl = ct2 * 32 + ((lane >> 4) * 8);
            half8 hv, lv;
#pragma unroll
            for (int j = 0; j < 8; ++j) {
                _Float16 hh, ll;
                split2(tile[nl][cl + j], hh, ll);
                hv[j] = hh; lv[j] = ll;
            }
            size_t u = ((size_t)((nb >> 4) + ntl) * 32 + (cb >> 5) + ct2) * 64 + lane;
            *(half8*)&Xhi[u * 8] = hv;
            *(half8*)&Xlo[u * 8] = lv;
        }
    }
}

// ---------------------- prep: single W^T -> planar planes (wo)
__global__ __launch_bounds__(256) void k_prep_wpl1(
    const float* __restrict__ W, _Float16* __restrict__ wpl)
{
    __shared__ float tile[64][65];
    _Float16* Whi = wpl;
    _Float16* Wlo = wpl + 1048576;
    const int kb = blockIdx.x * 64, cb = blockIdx.y * 64;
    const int t = threadIdx.x, r = t >> 4, c4 = (t & 15) * 4;
#pragma unroll
    for (int i = 0; i < 4; ++i) {
        int row = r + 16 * i;
        float4 v = *(const float4*)&W[(size_t)(kb + row) * 1024 + cb + c4];
        tile[row][c4 + 0] = v.x; tile[row][c4 + 1] = v.y;
        tile[row][c4 + 2] = v.z; tile[row][c4 + 3] = v.w;
    }
    __syncthreads();
#pragma unroll
    for (int h = 0; h < 2; ++h) {
        int idx = t + h * 256;
        int lane = idx & 63, kt2 = (idx >> 6) & 1, ct = idx >> 7;
        int cl = ct * 16 + (lane & 15);
        int kl = kt2 * 32 + ((lane >> 4) * 8);
        half8 hv, lv;
#pragma unroll
        for (int j = 0; j < 8; ++j) {
            _Float16 hh, ll;
            split2(tile[kl + j][cl], hh, ll);
            hv[j] = hh; lv[j] = ll;
        }
        size_t u = ((size_t)((cb >> 4) + ct) * 32 + (kb >> 5) + kt2) * 64 + lane;
        *(half8*)&Whi[u * 8] = hv;
        *(half8*)&Wlo[u * 8] = lv;
    }
}

// --------------------------------------------------- QKV GEMM (MFMA f16-split)
// Double-buffered LDS + early-issue global_load_lds, 1 barrier/iter.
__global__ __launch_bounds__(256) void k_gemm_qkv(
    const _Float16* __restrict__ xpl, const _Float16* __restrict__ wpl,
    const float* __restrict__ bq, const float* __restrict__ bk,
    const float* __restrict__ bv,
    float* __restrict__ qT, float* __restrict__ kT, float* __restrict__ vT)
{
    __shared__ __align__(16) _Float16 Ab[2][8][2][64][8];   // 32 KB
    __shared__ __align__(16) _Float16 Bb[2][8][2][64][8];   // 32 KB
    const int tid = threadIdx.x;
    const int mat = blockIdx.z;
    const _Float16* Ahi = wpl + (size_t)mat * 2097152;
    const _Float16* Alo = Ahi + 1048576;
    const _Float16* Bhi = xpl;
    const _Float16* Blo = xpl + 4194304;
    const float* bias = (mat == 0) ? bq : (mat == 1) ? bk : bv;
    float* outp       = (mat == 0) ? qT : (mat == 1) ? kT : vT;
    const int m0 = blockIdx.x * 128, n0 = blockIdx.y * 128;
    const int w = tid >> 6, lane = tid & 63, quad = lane >> 4, l15 = lane & 15;
    const int wm = (w & 1) * 4, wn = (w >> 1) * 4;

    const int s0 = 2 * w, s1 = 2 * w + 1;
    const size_t aT0 = (size_t)((m0 >> 4) + s0) * 32;
    const size_t aT1 = aT0 + 32;
    const size_t bT0 = (size_t)((n0 >> 4) + s0) * 32;
    const size_t bT1 = bT0 + 32;
    const int ln8 = lane * 8;

    f32x4 acc1[4][4], acc2[4][4];
    const f32x4 z4 = {0.f, 0.f, 0.f, 0.f};
#pragma unroll
    for (int i = 0; i < 4; ++i)
#pragma unroll
        for (int j = 0; j < 4; ++j) { acc1[i][j] = z4; acc2[i][j] = z4; }

    {
        size_t oA0 = aT0 * 512 + ln8;
        size_t oA1 = aT1 * 512 + ln8;
        size_t oB0 = bT0 * 512 + ln8;
        size_t oB1 = bT1 * 512 + ln8;
        GLOAD16(Ahi + oA0, &Ab[0][s0][0][0][0]);
        GLOAD16(Alo + oA0, &Ab[0][s0][1][0][0]);
        GLOAD16(Ahi + oA1, &Ab[0][s1][0][0][0]);
        GLOAD16(Alo + oA1, &Ab[0][s1][1][0][0]);
        GLOAD16(Bhi + oB0, &Bb[0][s0][0][0][0]);
        GLOAD16(Blo + oB0, &Bb[0][s0][1][0][0]);
        GLOAD16(Bhi + oB1, &Bb[0][s1][0][0][0]);
        GLOAD16(Blo + oB1, &Bb[0][s1][1][0][0]);
    }
    __syncthreads();

    for (int kt = 0; kt < 32; ++kt) {
        const int cur = kt & 1, nxt = cur ^ 1;
        if (kt < 31) {
            int kn = kt + 1;
            size_t oA0 = (aT0 + kn) * 512 + ln8;
            size_t oA1 = (aT1 + kn) * 512 + ln8;
            size_t oB0 = (bT0 + kn) * 512 + ln8;
            size_t oB1 = (bT1 + kn) * 512 + ln8;
            GLOAD16(Ahi + oA0, &Ab[nxt][s0][0][0][0]);
            GLOAD16(Alo + oA0, &Ab[nxt][s0][1][0][0]);
            GLOAD16(Ahi + oA1, &Ab[nxt][s1][0][0][0]);
            GLOAD16(Alo + oA1, &Ab[nxt][s1][1][0][0]);
            GLOAD16(Bhi + oB0, &Bb[nxt][s0][0][0][0]);
            GLOAD16(Blo + oB0, &Bb[nxt][s0][1][0][0]);
            GLOAD16(Bhi + oB1, &Bb[nxt][s1][0][0][0]);
            GLOAD16(Blo + oB1, &Bb[nxt][s1][1][0][0]);
        }
        half8 ah[4], al[4];
#pragma unroll
        for (int mt = 0; mt < 4; ++mt) {
            ah[mt] = *(half8*)&Ab[cur][wm + mt][0][lane][0];
            al[mt] = *(half8*)&Ab[cur][wm + mt][1][lane][0];
        }
#pragma unroll
        for (int nt = 0; nt < 4; ++nt) {
            half8 bh = *(half8*)&Bb[cur][wn + nt][0][lane][0];
            half8 bl = *(half8*)&Bb[cur][wn + nt][1][lane][0];
#pragma unroll
            for (int mt = 0; mt < 4; ++mt) {
                acc1[mt][nt] = MFMA16(ah[mt], bh, acc1[mt][nt], 0, 0, 0);
                acc2[mt][nt] = MFMA16(ah[mt], bl, acc2[mt][nt], 0, 0, 0);
                acc2[mt][nt] = MFMA16(al[mt], bh, acc2[mt][nt], 0, 0, 0);
            }
        }
        __syncthreads();
    }
    const int b_ = n0 >> 11, t0 = n0 & 2047;
#pragma unroll
    for (int mt = 0; mt < 4; ++mt) {
#pragma unroll
        for (int r_ = 0; r_ < 4; ++r_) {
            int m = m0 + (wm + mt) * 16 + quad * 4 + r_;
            float bs = bias[m];
            float* orow = &outp[(size_t)(b_ * 1024 + m) * 2048 + t0];
#pragma unroll
            for (int nt = 0; nt < 4; ++nt) {
                float val = acc1[mt][nt][r_] + acc2[mt][nt][r_] * (1.f / 2048.f) + bs;
                orow[(wn + nt) * 16 + l15] = val;
            }
        }
    }
}

// ------------------------------------------------------------- FFT + filter
// Real-FFT pairing + radix-4 butterflies + padded LDS (SFI).
#define SFI(i) ((i) + ((i) >> 4))
__global__ __launch_bounds__(256) void k_fft_filter(
    float* __restrict__ qT, float* __restrict__ kT, float* __restrict__ vT,
    float* __restrict__ qiT, float* __restrict__ kiT,
    const float2* __restrict__ tw, const float2* __restrict__ filt)
{
    __shared__ float2 sf[2176];          // 2048 + 128 pad
    const int bid = blockIdx.x;          // 0..3071
    const int mat = bid >> 10;
    const int pair = bid & 1023;
    const int seq0 = pair * 2, seq1 = seq0 + 1;
    float* base = (mat == 0) ? qT : (mat == 1) ? kT : vT;
    float* src0 = base + (size_t)seq0 * 2048;
    float* src1 = base + (size_t)seq1 * 2048;
    const int tid = threadIdx.x;

    for (int i = tid; i < 2048; i += 256) {
        int j = (int)(__brev((unsigned)i) >> 21);
        sf[SFI(j)] = make_float2(src0[i], src1[i]);
    }
    __syncthreads();
#pragma unroll
    for (int st = 1; st <= 9; st += 2) {
        const int h = 1 << (st - 1);
        const int s = 11 - st;
        for (int u = tid; u < 512; u += 256) {
            int m = u & (h - 1);
            int g = u >> (st - 1);
            int bi = g * 4 * h + m;
            float2 a = sf[SFI(bi)], b = sf[SFI(bi + h)];
            float2 c = sf[SFI(bi + 2 * h)], d = sf[SFI(bi + 3 * h)];
            float2 W  = tw[m << s];
            float2 W2 = tw[m << (s - 1)];
            float2 wb = cmul(W, b), wd = cmul(W, d);
            float2 a1 = make_float2(a.x + wb.x, a.y + wb.y);
            float2 b1 = make_float2(a.x - wb.x, a.y - wb.y);
            float2 c1 = make_float2(c.x + wd.x, c.y + wd.y);
            float2 d1 = make_float2(c.x - wd.x, c.y - wd.y);
            float2 w2c = cmul(W2, c1);
            float2 w2d = cmul(W2, d1);
            float2 w3d = make_float2(w2d.y, -w2d.x);   // -i * w2d
            sf[SFI(bi)]         = make_float2(a1.x + w2c.x, a1.y + w2c.y);
            sf[SFI(bi + 2 * h)] = make_float2(a1.x - w2c.x, a1.y - w2c.y);
            sf[SFI(bi + h)]     = make_float2(b1.x + w3d.x, b1.y + w3d.y);
            sf[SFI(bi + 3 * h)] = make_float2(b1.x - w3d.x, b1.y - w3d.y);
        }
        __syncthreads();
    }
    for (int u = tid; u < 1024; u += 256) {
        float2 w = tw[u];
        float2 a = sf[SFI(u)], b = sf[SFI(u + 1024)];
        float2 wb = cmul(w, b);
        sf[SFI(u)]        = make_float2(a.x + wb.x, a.y + wb.y);
        sf[SFI(u + 1024)] = make_float2(a.x - wb.x, a.y - wb.y);
    }
    __syncthreads();

    unsigned* dr0 = (unsigned*)src0;
    unsigned* dr1 = (unsigned*)src1;
    unsigned* di0 = (mat == 0) ? (unsigned*)(qiT + (size_t)seq0 * 2048)
                               : (unsigned*)(kiT + (size_t)seq0 * 2048);
    unsigned* di1 = (mat == 0) ? (unsigned*)(qiT + (size_t)seq1 * 2048)
                               : (unsigned*)(kiT + (size_t)seq1 * 2048);
    for (int i = tid; i < 2048; i += 256) {
        float2 z  = sf[SFI(i)];
        float2 zm = sf[SFI((2048 - i) & 2047)];
        float Are = 0.5f * (z.x + zm.x), Aim = 0.5f * (z.y - zm.y);
        float Bre = 0.5f * (z.y + zm.y), Bim = 0.5f * (zm.x - z.x);
        float2 f = filt[i];
        float re0 = Are * f.x - Aim * f.y, im0 = Are * f.y + Aim * f.x;
        float re1 = Bre * f.x - Bim * f.y, im1 = Bre * f.y + Bim * f.x;
        if (mat == 0) {
            dr0[i] = pack_split(0.125f * re0); di0[i] = pack_split(0.125f * im0);
            dr1[i] = pack_split(0.125f * re1); di1[i] = pack_split(0.125f * im1);
        } else if (mat == 1) {
            dr0[i] = pack_split(re0); di0[i] = pack_split(-im0);
            dr1[i] = pack_split(re1); di1[i] = pack_split(-im1);
        } else {
            dr0[i] = pack_split(re0);
            dr1[i] = pack_split(re1);
        }
    }
}

// ------------------------------------------------------------- flash (MFMA f16)
// R15/R16 verified version: 256 blocks x 512 thr (8 waves); wave owns 32 rows
// (2 rg, 128 apart); s-step 64; dbuf K/V, ONE barrier/iter; S^T=MFMA(K,Q);
// per-lane softmax + defer-max(THR=8); O^T=MFMA(V,P-reg); planar epilogue.
__global__ __launch_bounds__(512, 2) void k_flash(
    const unsigned* __restrict__ qpk, const unsigned* __restrict__ qipk,
    const unsigned* __restrict__ kpk, const unsigned* __restrict__ kipk,
    const unsigned* __restrict__ vpk, _Float16* __restrict__ attpl)
{
    __shared__ __align__(16) _Float16 Kbuf[2][4][4][2][64][8];  // 64KB
    __shared__ __align__(16) _Float16 Vbuf[2][2][4][2][64][8];  // 32KB

    const int tid = threadIdx.x;
    const int w = tid >> 6, lane = tid & 63;
    const int quad = lane >> 4, l15 = lane & 15;
    const int p = blockIdx.x;
    const int bh = (p & 7) * 4 + (p >> 6);
    const int tb = (p >> 3) & 7;
    const size_t bc = (size_t)bh * 64;
    const int tw0 = tb * 256 + w * 16;   // rg adds +128

    half8 aqh[2][4], aql[2][4];
#pragma unroll
    for (int rg = 0; rg < 2; ++rg) {
#pragma unroll
        for (int kc = 0; kc < 4; ++kc) {
#pragma unroll
            for (int j = 0; j < 8; ++j) {
                int d = kc * 32 + quad * 8 + j;
                int t = tw0 + rg * 128 + l15;
                unsigned u = (d < 64) ? qpk[(bc + d) * 2048 + t]
                                      : qipk[(bc + d - 64) * 2048 + t];
                aqh[rg][kc][j] = lo16(u);
                aql[rg][kc][j] = hi16(u);
            }
        }
    }

    f32x4 O1[2][4], O2[2][4];
    const f32x4 zero4 = {0.f, 0.f, 0.f, 0.f};
#pragma unroll
    for (int rg = 0; rg < 2; ++rg)
#pragma unroll
        for (int nt = 0; nt < 4; ++nt) { O1[rg][nt] = zero4; O2[rg][nt] = zero4; }
    float m_[2] = {-3e38f, -3e38f};
    float l_[2] = {0.f, 0.f};

    const int sK = tid & 63;
    const int dc0 = tid >> 6;
    const int stK = sK >> 4;
    const int kcK0 = dc0 >> 2;
    const int laneK = (sK & 15) + ((dc0 & 3) << 4);
    const unsigned* kre = &kpk[(bc + dc0 * 8) * 2048 + sK];
    const unsigned* kim = &kipk[(bc + dc0 * 8) * 2048 + sK];
    const int sc2V = tid >> 8;
    const int ntV = (tid >> 6) & 3, laneV = tid & 63;
    const int dV = ntV * 16 + (laneV & 15);
    const int s0V = sc2V * 32 + (laneV >> 4) * 4;
    const unsigned* vbase = &vpk[(bc + dV) * 2048 + s0V];

    unsigned ka0, ka1, ka2, ka3, ka4, ka5, ka6, ka7;
    unsigned kb0, kb1, kb2, kb3, kb4, kb5, kb6, kb7;
    uint4 va0, va1;
    ka0 = kre[0 * 2048]; ka1 = kre[1 * 2048];
    ka2 = kre[2 * 2048]; ka3 = kre[3 * 2048];
    ka4 = kre[4 * 2048]; ka5 = kre[5 * 2048];
    ka6 = kre[6 * 2048]; ka7 = kre[7 * 2048];
    kb0 = kim[0 * 2048]; kb1 = kim[1 * 2048];
    kb2 = kim[2 * 2048]; kb3 = kim[3 * 2048];
    kb4 = kim[4 * 2048]; kb5 = kim[5 * 2048];
    kb6 = kim[6 * 2048]; kb7 = kim[7 * 2048];
    va0 = *(const uint4*)vbase;
    va1 = *(const uint4*)(vbase + 16);
    write_split(&Kbuf[0][stK][kcK0][0][laneK][0], &Kbuf[0][stK][kcK0][1][laneK][0],
                make_uint4(ka0, ka1, ka2, ka3), make_uint4(ka4, ka5, ka6, ka7));
    write_split(&Kbuf[0][stK][kcK0 + 2][0][laneK][0], &Kbuf[0][stK][kcK0 + 2][1][laneK][0],
                make_uint4(kb0, kb1, kb2, kb3), make_uint4(kb4, kb5, kb6, kb7));
    write_split(&Vbuf[0][sc2V][ntV][0][laneV][0], &Vbuf[0][sc2V][ntV][1][laneV][0],
                va0, va1);
    kre += 64; kim += 64; vbase += 64;
    ka0 = kre[0 * 2048]; ka1 = kre[1 * 2048];
    ka2 = kre[2 * 2048]; ka3 = kre[3 * 2048];
    ka4 = kre[4 * 2048]; ka5 = kre[5 * 2048];
    ka6 = kre[6 * 2048]; ka7 = kre[7 * 2048];
    kb0 = kim[0 * 2048]; kb1 = kim[1 * 2048];
    kb2 = kim[2 * 2048]; kb3 = kim[3 * 2048];
    kb4 = kim[4 * 2048]; kb5 = kim[5 * 2048];
    kb6 = kim[6 * 2048]; kb7 = kim[7 * 2048];
    va0 = *(const uint4*)vbase;
    va1 = *(const uint4*)(vbase + 16);
    __syncthreads();

    for (int it = 0; it < 32; ++it) {
        const int cur = it & 1, nxt = cur ^ 1;
        if (it < 31) {
            write_split(&Kbuf[nxt][stK][kcK0][0][laneK][0],
                        &Kbuf[nxt][stK][kcK0][1][laneK][0],
                        make_uint4(ka0, ka1, ka2, ka3), make_uint4(ka4, ka5, ka6, ka7));
            write_split(&Kbuf[nxt][stK][kcK0 + 2][0][laneK][0],
                        &Kbuf[nxt][stK][kcK0 + 2][1][laneK][0],
                        make_uint4(kb0, kb1, kb2, kb3), make_uint4(kb4, kb5, kb6, kb7));
            write_split(&Vbuf[nxt][sc2V][ntV][0][laneV][0],
                        &Vbuf[nxt][sc2V][ntV][1][laneV][0], va0, va1);
        }
        if (it < 30) {
            kre += 64; kim += 64; vbase += 64;
            ka0 = kre[0 * 2048]; ka1 = kre[1 * 2048];
            ka2 = kre[2 * 2048]; ka3 = kre[3 * 2048];
            ka4 = kre[4 * 2048]; ka5 = kre[5 * 2048];
            ka6 = kre[6 * 2048]; ka7 = kre[7 * 2048];
            kb0 = kim[0 * 2048]; kb1 = kim[1 * 2048];
            kb2 = kim[2 * 2048]; kb3 = kim[3 * 2048];
            kb4 = kim[4 * 2048]; kb5 = kim[5 * 2048];
            kb6 = kim[6 * 2048]; kb7 = kim[7 * 2048];
            va0 = *(const uint4*)vbase;
            va1 = *(const uint4*)(vbase + 16);
        }

        // --- S^T = K.Q^T: 96 MFMA, K read once
        f32x4 S1[2][4], S2[2][4];
#pragma unroll
        for (int rg = 0; rg < 2; ++rg)
#pragma unroll
            for (int st = 0; st < 4; ++st) { S1[rg][st] = zero4; S2[rg][st] = zero4; }
        __builtin_amdgcn_s_setprio(1);
#pragma unroll
        for (int st = 0; st < 4; ++st) {
#pragma unroll
            for (int kc = 0; kc < 4; ++kc) {
                half8 khf = *(half8*)&Kbuf[cur][st][kc][0][lane][0];
                half8 klf = *(half8*)&Kbuf[cur][st][kc][1][lane][0];
#pragma unroll
                for (int rg = 0; rg < 2; ++rg) {
                    S1[rg][st] = MFMA16(khf, aqh[rg][kc], S1[rg][st], 0, 0, 0);
                    S2[rg][st] = MFMA16(klf, aqh[rg][kc], S2[rg][st], 0, 0, 0);
                    S2[rg][st] = MFMA16(khf, aql[rg][kc], S2[rg][st], 0, 0, 0);
                }
            }
        }
        __builtin_amdgcn_s_setprio(0);

        // --- per-lane online softmax with defer-max (THR=8)
        half8 pb[2][2];
#pragma unroll
        for (int rg = 0; rg < 2; ++rg) {
#pragma unroll
            for (int st = 0; st < 4; ++st)
                S1[rg][st] = S1[rg][st] + S2[rg][st] * (1.f / 2048.f);
            float mt = -3e38f;
#pragma unroll
            for (int st = 0; st < 4; ++st)
#pragma unroll
                for (int r = 0; r < 4; ++r)
                    mt = fmaxf(mt, S1[rg][st][r]);
            mt = fmaxf(mt, __shfl_xor(mt, 16));
            mt = fmaxf(mt, __shfl_xor(mt, 32));
            if (!__all(mt <= m_[rg] + 8.f)) {
                float mn2 = fmaxf(m_[rg], mt);
                float al = __expf(m_[rg] - mn2);
                m_[rg] = mn2;
                l_[rg] *= al;
#pragma unroll
                for (int nt = 0; nt < 4; ++nt) { O1[rg][nt] *= al; O2[rg][nt] *= al; }
            }
            float mn = m_[rg];
            float rs = 0.f;
            _Float16 ph[4][4];
#pragma unroll
            for (int st = 0; st < 4; ++st)
#pragma unroll
                for (int r = 0; r < 4; ++r) {
                    float pe = __expf(S1[rg][st][r] - mn);
                    rs += pe;
                    ph[st][r] = (_Float16)pe;
                }
            rs += __shfl_xor(rs, 16);
            rs += __shfl_xor(rs, 32);
            l_[rg] += rs;
#pragma unroll
            for (int sc2 = 0; sc2 < 2; ++sc2) {
                half8 t8;
                t8[0] = ph[2 * sc2][0];     t8[1] = ph[2 * sc2][1];
                t8[2] = ph[2 * sc2][2];     t8[3] = ph[2 * sc2][3];
                t8[4] = ph[2 * sc2 + 1][0]; t8[5] = ph[2 * sc2 + 1][1];
                t8[6] = ph[2 * sc2 + 1][2]; t8[7] = ph[2 * sc2 + 1][3];
                pb[rg][sc2] = t8;
            }
        }

        // --- PV as O^T = MFMA(Vfrag, P): 32 MFMA
        __builtin_amdgcn_s_setprio(1);
#pragma unroll
        for (int sc2 = 0; sc2 < 2; ++sc2) {
#pragma unroll
            for (int nt = 0; nt < 4; ++nt) {
                half8 vh = *(half8*)&Vbuf[cur][sc2][nt][0][lane][0];
                half8 vl = *(half8*)&Vbuf[cur][sc2][nt][1][lane][0];
                O1[0][nt] = MFMA16(vh, pb[0][sc2], O1[0][nt], 0, 0, 0);
                O2[0][nt] = MFMA16(vl, pb[0][sc2], O2[0][nt], 0, 0, 0);
                O1[1][nt] = MFMA16(vh, pb[1][sc2], O1[1][nt], 0, 0, 0);
                O2[1][nt] = MFMA16(vl, pb[1][sc2], O2[1][nt], 0, 0, 0);
            }
        }
        __builtin_amdgcn_s_setprio(0);

        __syncthreads();
    }

    // epilogue: write planar planes.
    const int b = bh >> 4, h = bh & 15;
#pragma unroll
    for (int rg = 0; rg < 2; ++rg) {
        float inv = 1.0f / l_[rg];
        int mrow = b * 2048 + tw0 + rg * 128 + l15;
        size_t mt32 = (size_t)(mrow >> 4) * 32;
#pragma unroll
        for (int nt = 0; nt < 4; ++nt) {
            size_t u = (mt32 + h * 2 + (nt >> 1)) * 512
                     + (size_t)(l15 + 16 * ((nt * 2 + (quad >> 1)) & 3)) * 8
                     + (quad & 1) * 4;
            half4 hv, lv;
#pragma unroll
            for (int r = 0; r < 4; ++r) {
                float val = (O1[rg][nt][r] + O2[rg][nt][r] * (1.f / 2048.f)) * inv;
                _Float16 hh, ll;
                split2(val, hh, ll);
                hv[r] = hh; lv[r] = ll;
            }
            *(half4*)&attpl[u] = hv;
            *(half4*)&attpl[4194304 + u] = lv;
        }
    }
}

// --------------------------------------------------- out GEMM (MFMA f16-split)
__global__ __launch_bounds__(256) void k_gemm_out(
    const _Float16* __restrict__ attpl, const _Float16* __restrict__ wopl,
    const float* __restrict__ bo, float* __restrict__ out)
{
    __shared__ __align__(16) _Float16 Ab[2][8][2][64][8];   // 32 KB
    __shared__ __align__(16) _Float16 Bb[2][8][2][64][8];   // 32 KB
    const int tid = threadIdx.x;
    const _Float16* Ahi = attpl;
    const _Float16* Alo = attpl + 4194304;
    const _Float16* Bhi = wopl;
    const _Float16* Blo = wopl + 1048576;
    const int m0 = blockIdx.x * 128, n0 = blockIdx.y * 128;
    const int w = tid >> 6, lane = tid & 63, quad = lane >> 4, l15 = lane & 15;
    const int wm = (w & 1) * 4, wn = (w >> 1) * 4;

    const int s0 = 2 * w, s1 = 2 * w + 1;
    const size_t aT0 = (size_t)((m0 >> 4) + s0) * 32;
    const size_t aT1 = aT0 + 32;
    const size_t bT0 = (size_t)((n0 >> 4) + s0) * 32;
    const size_t bT1 = bT0 + 32;
    const int ln8 = lane * 8;

    f32x4 acc1[4][4], acc2[4][4];
    const f32x4 z4 = {0.f, 0.f, 0.f, 0.f};
#pragma unroll
    for (int i = 0; i < 4; ++i)
#pragma unroll
        for (int j = 0; j < 4; ++j) { acc1[i][j] = z4; acc2[i][j] = z4; }

    {
        size_t oA0 = aT0 * 512 + ln8;
        size_t oA1 = aT1 * 512 + ln8;
        size_t oB0 = bT0 * 512 + ln8;
        size_t oB1 = bT1 * 512 + ln8;
        GLOAD16(Ahi + oA0, &Ab[0][s0][0][0][0]);
        GLOAD16(Alo + oA0, &Ab[0][s0][1][0][0]);
        GLOAD16(Ahi + oA1, &Ab[0][s1][0][0][0]);
        GLOAD16(Alo + oA1, &Ab[0][s1][1][0][0]);
        GLOAD16(Bhi + oB0, &Bb[0][s0][0][0][0]);
        GLOAD16(Blo + oB0, &Bb[0][s0][1][0][0]);
        GLOAD16(Bhi + oB1, &Bb[0][s1][0][0][0]);
        GLOAD16(Blo + oB1, &Bb[0][s1][1][0][0]);
    }
    __syncthreads();

    for (int kt = 0; kt < 32; ++kt) {
        const int cur = kt & 1, nxt = cur ^ 1;
        if (kt < 31) {
            int kn = kt + 1;
            size_t oA0 = (aT0 + kn) * 512 + ln8;
            size_t oA1 = (aT1 + kn) * 512 + ln8;
            size_t oB0 = (bT0 + kn) * 512 + ln8;
            size_t oB1 = (bT1 + kn) * 512 + ln8;
            GLOAD16(Ahi + oA0, &Ab[nxt][s0][0][0][0]);
            GLOAD16(Alo + oA0, &Ab[nxt][s0][1][0][0]);
            GLOAD16(Ahi + oA1, &Ab[nxt][s1][0][0][0]);
            GLOAD16(Alo + oA1, &Ab[nxt][s1][1][0][0]);
            GLOAD16(Bhi + oB0, &Bb[nxt][s0][0][0][0]);
            GLOAD16(Blo + oB0, &Bb[nxt][s0][1][0][0]);
            GLOAD16(Bhi + oB1, &Bb[nxt][s1][0][0][0]);
            GLOAD16(Blo + oB1, &Bb[nxt][s1][1][0][0]);
        }
        half8 ah[4], al[4];
#pragma unroll
        for (int mt = 0; mt < 4; ++mt) {
            ah[mt] = *(half8*)&Ab[cur][wm + mt][0][lane][0];
            al[mt] = *(half8*)&Ab[cur][wm + mt][1][lane][0];
        }
#pragma unroll
        for (int nt = 0; nt < 4; ++nt) {
            half8 bh = *(half8*)&Bb[cur][wn + nt][0][lane][0];
            half8 bl = *(half8*)&Bb[cur][wn + nt][1][lane][0];
#pragma unroll
            for (int mt = 0; mt < 4; ++mt) {
                acc1[mt][nt] = MFMA16(ah[mt], bh, acc1[mt][nt], 0, 0, 0);
                acc2[mt][nt] = MFMA16(ah[mt], bl, acc2[mt][nt], 0, 0, 0);
                acc2[mt][nt] = MFMA16(al[mt], bh, acc2[mt][nt], 0, 0, 0);
            }
        }
        __syncthreads();
    }
#pragma unroll
    for (int mt = 0; mt < 4; ++mt) {
#pragma unroll
        for (int r_ = 0; r_ < 4; ++r_) {
            int m = m0 + (wm + mt) * 16 + quad * 4 + r_;
            float* orow = &out[(size_t)m * 1024 + n0];
#pragma unroll
            for (int nt = 0; nt < 4; ++nt) {
                int n = (wn + nt) * 16 + l15;
                float val = acc1[mt][nt][r_] + acc2[mt][nt][r_] * (1.f / 2048.f)
                          + bo[n0 + n];
                orow[n] = val;
            }
        }
    }
}

// ------------------------------------------------------------- energy renorm
__global__ __launch_bounds__(256) void k_norm(
    const float* __restrict__ x, float* __restrict__ out,
    const float* __restrict__ en)
{
    const int row = blockIdx.x;
    const int tid = threadIdx.x;
    const float* xr = x + (size_t)row * 1024;
    float* orow = out + (size_t)row * 1024;
    float4 xv = *(const float4*)&xr[tid * 4];
    float4 ov = *(const float4*)&orow[tid * 4];
    float ssx = xv.x * xv.x + xv.y * xv.y + xv.z * xv.z + xv.w * xv.w;
    float sso = ov.x * ov.x + ov.y * ov.y + ov.z * ov.z + ov.w * ov.w;
#pragma unroll
    for (int m = 1; m <= 32; m <<= 1) {
        ssx += __shfl_xor(ssx, m, 64);
        sso += __shfl_xor(sso, m, 64);
    }
    __shared__ float rx[4], ro[4];
    const int wid = tid >> 6;
    if ((tid & 63) == 0) { rx[wid] = ssx; ro[wid] = sso; }
    __syncthreads();
    float tsx = rx[0] + rx[1] + rx[2] + rx[3];
    float tso = ro[0] + ro[1] + ro[2] + ro[3];
    float scale = sqrtf(tsx) / (sqrtf(tso) + 1e-8f) * en[0];
    ov.x *= scale; ov.y *= scale; ov.z *= scale; ov.w *= scale;
    *(float4*)&orow[tid * 4] = ov;
}

// ------------------------------------------------------------- launch
extern "C" void kernel_launch(void* const* d_in, const int* in_sizes, int n_in,
                              void* d_out, int out_size, void* d_ws, size_t ws_size,
                              hipStream_t stream)
{
    const float* x     = (const float*)d_in[0];
    const float* fd    = (const float*)d_in[1];
    const float* wq    = (const float*)d_in[2];
    const float* bq    = (const float*)d_in[3];
    const float* wk    = (const float*)d_in[4];
    const float* bk    = (const float*)d_in[5];
    const float* wv    = (const float*)d_in[6];
    const float* bv    = (const float*)d_in[7];
    const float* wo    = (const float*)d_in[8];
    const float* bo    = (const float*)d_in[9];
    const float* alpha = (const float*)d_in[10];
    const float* fas   = (const float*)d_in[11];
    const float* en    = (const float*)d_in[12];
    float* out = (float*)d_out;
    float* ws  = (float*)d_ws;

    float* qT  = ws;                               // -> qpk -> wopl
    float* kT  = ws + (size_t)1 * 4194304;         // -> kpk
    float* vT  = ws + (size_t)2 * 4194304;         // -> vpk
    float* qiT = ws + (size_t)3 * 4194304;         // w-planes -> qipk
    float* kiT = ws + (size_t)4 * 4194304;         // -> kipk
    float* att = ws + (size_t)5 * 4194304;         // x-planes -> att-planes
    float2* tw   = (float2*)(ws + (size_t)6 * 4194304);
    float2* filt = (float2*)(ws + (size_t)6 * 4194304 + 2048);

    _Float16* wpl   = (_Float16*)qiT;    // 3 x (2MB hi + 2MB lo) = 12MB
    _Float16* xpl   = (_Float16*)att;    // 8MB hi + 8MB lo = 16MB
    _Float16* attpl = (_Float16*)att;    // 8MB hi + 8MB lo (after xpl dead)
    _Float16* wopl  = (_Float16*)qT;     // 2MB hi + 2MB lo (after flash)

    k_prep_front<<<1800, 256, 0, stream>>>(tw, filt, fd, alpha, fas,
                                           wq, wk, wv, wpl, x, xpl);
    k_gemm_qkv<<<dim3(8, 32, 3), 256, 0, stream>>>(xpl, wpl, bq, bk, bv,
                                                   qT, kT, vT);
    k_fft_filter<<<3072, 256, 0, stream>>>(qT, kT, vT, qiT, kiT, tw, filt);
    k_flash<<<256, 512, 0, stream>>>((const unsigned*)qT, (const unsigned*)qiT,
                                     (const unsigned*)kT, (const unsigned*)kiT,
                                     (const unsigned*)vT, attpl);
    k_prep_wpl1<<<dim3(16, 16), 256, 0, stream>>>(wo, wopl);
    k_gemm_out<<<dim3(32, 8), 256, 0, stream>>>(attpl, wopl, bo, out);
    k_norm<<<4096, 256, 0, stream>>>(x, out, en);
}